// Round 1
// baseline (467.909 us; speedup 1.0000x reference)
//
#include <hip/hip_runtime.h>
#include <hip/hip_bf16.h>

// NeighborConsistencyLoss: loss = mean_s(1 - mean_k cos(z[c_s], z[knn[c_s,k]]))
//   z:[N,512] f32, knn:[N,32] i32, samp:[S] i32 -> scalar f32.
// Memory-bound gather: ~66 MB HBM reads. One block (256 thr = 4 waves) per
// sample; center fragment lives in registers (8 floats/lane), each wave
// handles 8 of the 32 neighbors.

#define DDIM 512
#define KNN 32
#define EPSV 1e-8f

__global__ __launch_bounds__(256) void ncl_pair_kernel(
    const float* __restrict__ z,
    const int* __restrict__ knn,
    const int* __restrict__ samp,
    float* __restrict__ block_sums) {
    const int s    = blockIdx.x;
    const int lane = threadIdx.x & 63;
    const int wave = threadIdx.x >> 6;

    const int cidx = samp[s];
    const float4* __restrict__ crow = (const float4*)(z + (size_t)cidx * DDIM);
    // lane's center fragment: elements [lane*4 .. lane*4+3] and [256+lane*4 ..]
    const float4 c0 = crow[lane];
    const float4 c1 = crow[64 + lane];

    // center squared norm (wave-reduced; identical in all 4 waves — cheap)
    float cn = c0.x*c0.x + c0.y*c0.y + c0.z*c0.z + c0.w*c0.w
             + c1.x*c1.x + c1.y*c1.y + c1.z*c1.z + c1.w*c1.w;
    #pragma unroll
    for (int off = 32; off; off >>= 1) cn += __shfl_xor(cn, off, 64);
    const float cnorm = sqrtf(cn);

    const int* __restrict__ krow = knn + (size_t)cidx * KNN;

    float wsum = 0.0f;
    #pragma unroll
    for (int kk = 0; kk < KNN / 4; ++kk) {
        const int k    = wave + kk * 4;
        const int nidx = krow[k];
        const float4* __restrict__ nrow = (const float4*)(z + (size_t)nidx * DDIM);
        const float4 n0 = nrow[lane];
        const float4 n1 = nrow[64 + lane];

        float dp = c0.x*n0.x; float nn = n0.x*n0.x;
        dp = fmaf(c0.y, n0.y, dp); nn = fmaf(n0.y, n0.y, nn);
        dp = fmaf(c0.z, n0.z, dp); nn = fmaf(n0.z, n0.z, nn);
        dp = fmaf(c0.w, n0.w, dp); nn = fmaf(n0.w, n0.w, nn);
        dp = fmaf(c1.x, n1.x, dp); nn = fmaf(n1.x, n1.x, nn);
        dp = fmaf(c1.y, n1.y, dp); nn = fmaf(n1.y, n1.y, nn);
        dp = fmaf(c1.z, n1.z, dp); nn = fmaf(n1.z, n1.z, nn);
        dp = fmaf(c1.w, n1.w, dp); nn = fmaf(n1.w, n1.w, nn);

        #pragma unroll
        for (int off = 32; off; off >>= 1) {
            dp += __shfl_xor(dp, off, 64);
            nn += __shfl_xor(nn, off, 64);
        }
        const float denom = fmaxf(cnorm * sqrtf(nn), EPSV);
        wsum += dp / denom;
    }

    __shared__ float red[4];
    if (lane == 0) red[wave] = wsum;
    __syncthreads();
    if (threadIdx.x == 0)
        block_sums[s] = red[0] + red[1] + red[2] + red[3];
}

__global__ __launch_bounds__(256) void ncl_finalize_kernel(
    const float* __restrict__ block_sums, float* __restrict__ out, int S) {
    __shared__ float red[256];
    float acc = 0.0f;
    for (int i = threadIdx.x; i < S; i += 256) acc += block_sums[i];
    red[threadIdx.x] = acc;
    __syncthreads();
    #pragma unroll
    for (int off = 128; off; off >>= 1) {
        if (threadIdx.x < off) red[threadIdx.x] += red[threadIdx.x + off];
        __syncthreads();
    }
    if (threadIdx.x == 0)
        out[0] = 1.0f - red[0] / ((float)S * (float)KNN);
}

extern "C" void kernel_launch(void* const* d_in, const int* in_sizes, int n_in,
                              void* d_out, int out_size, void* d_ws, size_t ws_size,
                              hipStream_t stream) {
    const float* z    = (const float*)d_in[0];
    const int*   knn  = (const int*)d_in[1];
    const int*   samp = (const int*)d_in[2];
    const int    S    = in_sizes[2];

    float* block_sums = (float*)d_ws;  // S floats of scratch
    float* out        = (float*)d_out;

    ncl_pair_kernel<<<S, 256, 0, stream>>>(z, knn, samp, block_sums);
    ncl_finalize_kernel<<<1, 256, 0, stream>>>(block_sums, out, S);
}